// Round 2
// baseline (2591.247 us; speedup 1.0000x reference)
//
#include <hip/hip_runtime.h>
#include <math.h>

#define HW 16384            // 128*128
#define PS 16900            // 130*130 padded plane
// ---------------------------------------------------------------- workspace
// ccpad : 512*PS floats  (ch 0..255 = upsampled x, ch 256..511 = Cf)
// offb  : 18*HW floats   (offset conv output, bias NOT included)
// IDX   : 9*HW int4      (4 gather indices per (k,pixel))
// WT    : 9*HW float4    (4 bilinear weights)
// dcwT  : 9*512*256      (dc_w transposed to [k][c][o])
// bufA  : 256*PS         (v flat, then fampad)   -- aliased; ring zeroed AFTER v consumed
// bufB  : 256*PS         (u flat, then up1pad)   -- aliased; ring zeroed AFTER u consumed

// ---- zero the pad ring of nch padded planes at base ------------------------
__global__ __launch_bounds__(256) void zero_ring_k(float* __restrict__ base, int nch) {
    int t = blockIdx.x * 256 + threadIdx.x;
    if (t >= nch * 516) return;
    int ch = t / 516, rp = t - ch * 516;
    int row, col;
    if (rp < 130)      { row = 0;   col = rp; }
    else if (rp < 260) { row = 129; col = rp - 130; }
    else { int rem = rp - 260; row = 1 + (rem >> 1); col = (rem & 1) ? 129 : 0; }
    base[(size_t)ch * PS + row * 130 + col] = 0.0f;
}

// ---- bilinear upsample (align_corners) 32x32 -> 128x128, into padded cc ----
__global__ __launch_bounds__(256) void upsample_k(const float* __restrict__ x,
                                                  float* __restrict__ ccpad) {
    int c = blockIdx.y;
    int idx = blockIdx.x * 256 + threadIdx.x;
    if (idx >= PS) return;
    int r = idx / 130, s = idx - r * 130;
    float val = 0.0f;
    if (r >= 1 && r <= 128 && s >= 1 && s <= 128) {
        int i = r - 1, j = s - 1;
        float yf = (float)i * (31.0f / 127.0f);
        float xf = (float)j * (31.0f / 127.0f);
        int y0 = min((int)yf, 31); int y1 = min(y0 + 1, 31);
        int x0 = min((int)xf, 31); int x1 = min(x0 + 1, 31);
        float wy = yf - (float)y0, wx = xf - (float)x0;
        const float* xc = x + (size_t)c * 1024;
        float a = xc[y0 * 32 + x0] * (1.0f - wx) + xc[y0 * 32 + x1] * wx;
        float b = xc[y1 * 32 + x0] * (1.0f - wx) + xc[y1 * 32 + x1] * wx;
        val = a * (1.0f - wy) + b * wy;
    }
    ccpad[(size_t)c * PS + idx] = val;
}

// ---- 1x1 "conv" GEMM out[o,p] = sum_c W[o,c]*in[c,p]; sigmoid variant ------
__global__ __launch_bounds__(256) void gemm1x1_sig_k(const float* __restrict__ wmat,
                                                     const float* __restrict__ in,
                                                     float* __restrict__ out) {
    __shared__ float wl[2048];
    int tid = threadIdx.x;
    int o0 = blockIdx.y << 3;
    for (int i = tid; i < 2048; i += 256) wl[i] = wmat[(o0 << 8) + i];
    __syncthreads();
    int p = (blockIdx.x << 10) + (tid << 2);
    float4 acc[8];
#pragma unroll
    for (int j = 0; j < 8; ++j) acc[j] = make_float4(0.f, 0.f, 0.f, 0.f);
    for (int c = 0; c < 256; ++c) {
        float4 z = *(const float4*)(in + (size_t)c * HW + p);
#pragma unroll
        for (int j = 0; j < 8; ++j) {
            float wj = wl[(j << 8) + c];
            acc[j].x += wj * z.x; acc[j].y += wj * z.y;
            acc[j].z += wj * z.z; acc[j].w += wj * z.w;
        }
    }
#pragma unroll
    for (int j = 0; j < 8; ++j) {
        float4 r;
        r.x = 1.0f / (1.0f + expf(-acc[j].x));
        r.y = 1.0f / (1.0f + expf(-acc[j].y));
        r.z = 1.0f / (1.0f + expf(-acc[j].z));
        r.w = 1.0f / (1.0f + expf(-acc[j].w));
        *(float4*)(out + (size_t)(o0 + j) * HW + p) = r;
    }
}

// ---- same GEMM, no activation, writes into padded planes (Cf -> ccpad) -----
__global__ __launch_bounds__(256) void gemm1x1_pad_k(const float* __restrict__ wmat,
                                                     const float* __restrict__ in,
                                                     float* __restrict__ outpad) {
    __shared__ float wl[2048];
    int tid = threadIdx.x;
    int o0 = blockIdx.y << 3;
    for (int i = tid; i < 2048; i += 256) wl[i] = wmat[(o0 << 8) + i];
    __syncthreads();
    int p = (blockIdx.x << 10) + (tid << 2);
    float4 acc[8];
#pragma unroll
    for (int j = 0; j < 8; ++j) acc[j] = make_float4(0.f, 0.f, 0.f, 0.f);
    for (int c = 0; c < 256; ++c) {
        float4 z = *(const float4*)(in + (size_t)c * HW + p);
#pragma unroll
        for (int j = 0; j < 8; ++j) {
            float wj = wl[(j << 8) + c];
            acc[j].x += wj * z.x; acc[j].y += wj * z.y;
            acc[j].z += wj * z.z; acc[j].w += wj * z.w;
        }
    }
    int h = p >> 7, w = p & 127;
#pragma unroll
    for (int j = 0; j < 8; ++j) {
        float* dst = outpad + (size_t)(o0 + j) * PS + (h + 1) * 130 + (w + 1);
        dst[0] = acc[j].x; dst[1] = acc[j].y; dst[2] = acc[j].z; dst[3] = acc[j].w;
    }
}

// ---- u[c,h,w] = sum_k L[c,h,k]*v[c,k,w] + L[c,h,w]  (per-channel matmul) ---
__global__ __launch_bounds__(256) void u_matmul_k(const float* __restrict__ llf,
                                                  const float* __restrict__ v,
                                                  float* __restrict__ u) {
    int c = blockIdx.y;
    const float* L = llf + (size_t)c * HW;
    const float* V = v   + (size_t)c * HW;
    float*       U = u   + (size_t)c * HW;
    int tid = threadIdx.x;
    int ty = tid >> 4, tx = tid & 15;
    int r0 = (blockIdx.x << 6) + (ty << 2);
    int w0 = tx << 3;
    float acc[4][8] = {};
    for (int k = 0; k < 128; ++k) {
        float a[4];
#pragma unroll
        for (int i = 0; i < 4; ++i) a[i] = L[(r0 + i) * 128 + k];
        float4 b0 = *(const float4*)(V + k * 128 + w0);
        float4 b1 = *(const float4*)(V + k * 128 + w0 + 4);
        float bv[8] = {b0.x, b0.y, b0.z, b0.w, b1.x, b1.y, b1.z, b1.w};
#pragma unroll
        for (int i = 0; i < 4; ++i)
#pragma unroll
            for (int j = 0; j < 8; ++j) acc[i][j] += a[i] * bv[j];
    }
#pragma unroll
    for (int i = 0; i < 4; ++i) {
#pragma unroll
        for (int j = 0; j < 8; ++j) acc[i][j] += L[(r0 + i) * 128 + w0 + j];
        *(float4*)(U + (r0 + i) * 128 + w0)     = make_float4(acc[i][0], acc[i][1], acc[i][2], acc[i][3]);
        *(float4*)(U + (r0 + i) * 128 + w0 + 4) = make_float4(acc[i][4], acc[i][5], acc[i][6], acc[i][7]);
    }
}

// ---- offset conv: 3x3, 512 -> 18 channels, on padded cc (no bias) ----------
__global__ __launch_bounds__(256) void off_conv_k(const float* __restrict__ ccpad,
                                                  const float* __restrict__ pw,
                                                  float* __restrict__ offb) {
    int o = blockIdx.y;                       // 0..17
    int p = blockIdx.x * 256 + threadIdx.x;   // 0..16383
    int h = p >> 7, w = p & 127;
    const float* wb = pw + (size_t)o * 512 * 9;
    float acc = 0.0f;
    for (int c = 0; c < 512; ++c) {
        const float* ib = ccpad + (size_t)c * PS + h * 130 + w;
        const float* wc = wb + c * 9;
        acc += ib[0]   * wc[0] + ib[1]   * wc[1] + ib[2]   * wc[2]
             + ib[130] * wc[3] + ib[131] * wc[4] + ib[132] * wc[5]
             + ib[260] * wc[6] + ib[261] * wc[7] + ib[262] * wc[8];
    }
    offb[(size_t)o * HW + p] = acc;
}

// ---- per-(pixel, k): 4 gather indices into 130x130 plane + 4 weights -------
__global__ __launch_bounds__(256) void make_idx_k(const float* __restrict__ offb,
                                                  const float* __restrict__ pb,
                                                  int4* __restrict__ IDX,
                                                  float4* __restrict__ WT) {
    int t = blockIdx.x * 256 + threadIdx.x;
    if (t >= 9 * HW) return;
    int k = t >> 14, p = t & 16383;
    int h = p >> 7, w = p & 127;
    float px = offb[(size_t)k * HW + p]       + pb[k]     + (float)(k / 3 - 1) + (float)(h + 1);
    float py = offb[(size_t)(9 + k) * HW + p] + pb[9 + k] + (float)(k % 3 - 1) + (float)(w + 1);
    float fx = floorf(px), fy = floorf(py);
    float x0 = fminf(fmaxf(fx,        0.f), 129.f);
    float x1 = fminf(fmaxf(fx + 1.0f, 0.f), 129.f);
    float y0 = fminf(fmaxf(fy,        0.f), 129.f);
    float y1 = fminf(fmaxf(fy + 1.0f, 0.f), 129.f);
    float pxc = fminf(fmaxf(px, 0.f), 129.f);
    float pyc = fminf(fmaxf(py, 0.f), 129.f);
    float gx0 = 1.0f + x0 - pxc, gx1 = 1.0f - x1 + pxc;
    float gy0 = 1.0f + y0 - pyc, gy1 = 1.0f - y1 + pyc;
    int ix0 = (int)x0, ix1 = (int)x1, iy0 = (int)y0, iy1 = (int)y1;
    IDX[t] = make_int4(ix0 * 130 + iy0, ix1 * 130 + iy1, ix0 * 130 + iy1, ix1 * 130 + iy0);
    WT[t]  = make_float4(gx0 * gy0, gx1 * gy1, gx0 * gy1, gx1 * gy0);
}

// ---- transpose dc_w (256,512,3,3) -> dcwT[k][c][o] -------------------------
__global__ __launch_bounds__(256) void transpose_dcw_k(const float* __restrict__ dcw,
                                                       float* __restrict__ dcwT) {
    int t = blockIdx.x * 256 + threadIdx.x;
    if (t >= 9 * 512 * 256) return;
    int o = t & 255, c = (t >> 8) & 511, k = t >> 17;
    dcwT[t] = dcw[(size_t)o * 4608 + c * 9 + k];
}

// ---- deformable contraction: fam[o,pix] = sum_{k,c} dcwT[k][c][o]*gather + Cf
// grid (128 pixel-rows, 4 o-tiles of 64); k-loop internal, register acc.
__global__ __launch_bounds__(256) void fam_gemm_k(const float* __restrict__ ccpad,
                                                  const float* __restrict__ dcwT,
                                                  const int4* __restrict__ IDX,
                                                  const float4* __restrict__ WT,
                                                  float* __restrict__ fampad) {
    __shared__ __align__(16) float As[16][64];    // [c-chunk][o]
    __shared__ __align__(16) float Bs[16][128];   // [c-chunk][pixel]
    int tid = threadIdx.x;
    int ty = tid >> 4, tx = tid & 15;
    int hrow = blockIdx.x;             // pixel row (pixels hrow*128 .. +127)
    int o0 = blockIdx.y << 6;
    int pp = tid & 127, g = tid >> 7;  // gather assignment
    float acc[4][8] = {};
    for (int k = 0; k < 9; ++k) {
        int4   id = IDX[(k << 14) + (hrow << 7) + pp];
        float4 wt = WT [(k << 14) + (hrow << 7) + pp];
        const float* dk = dcwT + (size_t)k * 512 * 256;
        for (int ks = 0; ks < 512; ks += 16) {
            __syncthreads();
            // stage A (coalesced rows of 64 along o)
#pragma unroll
            for (int j = 0; j < 4; ++j) {
                int ii = tid + (j << 8);
                As[ii >> 6][ii & 63] = dk[(size_t)(ks + (ii >> 6)) * 256 + o0 + (ii & 63)];
            }
            // stage B via bilinear gather (idx/wt shared across channels)
#pragma unroll
            for (int j = 0; j < 8; ++j) {
                int cc = g + (j << 1);
                const float* cb = ccpad + (size_t)(ks + cc) * PS;
                Bs[cc][pp] = wt.x * cb[id.x] + wt.y * cb[id.y]
                           + wt.z * cb[id.z] + wt.w * cb[id.w];
            }
            __syncthreads();
#pragma unroll
            for (int cc = 0; cc < 16; ++cc) {
                float4 a4 = *(const float4*)(&As[cc][ty << 2]);
                float4 b0 = *(const float4*)(&Bs[cc][tx << 3]);
                float4 b1 = *(const float4*)(&Bs[cc][(tx << 3) + 4]);
                float av[4] = {a4.x, a4.y, a4.z, a4.w};
                float bv[8] = {b0.x, b0.y, b0.z, b0.w, b1.x, b1.y, b1.z, b1.w};
#pragma unroll
                for (int i = 0; i < 4; ++i)
#pragma unroll
                    for (int j = 0; j < 8; ++j) acc[i][j] += av[i] * bv[j];
            }
        }
    }
    size_t rowoff = (size_t)(hrow + 1) * 130;
#pragma unroll
    for (int i = 0; i < 4; ++i) {
        int o = o0 + (ty << 2) + i;
#pragma unroll
        for (int j = 0; j < 8; ++j) {
            int col = (tx << 3) + j + 1;
            fampad[(size_t)o * PS + rowoff + col] =
                acc[i][j] + ccpad[(size_t)(256 + o) * PS + rowoff + col];
        }
    }
}

// ---- 3x3 conv 256->256 on padded input + BN(eval) + ReLU -------------------
__global__ __launch_bounds__(256) void conv3x3_bnrelu_k(const float* __restrict__ inpad,
                                                        const float* __restrict__ wgt,
                                                        const float* __restrict__ gamma,
                                                        const float* __restrict__ beta,
                                                        const float* __restrict__ mean,
                                                        const float* __restrict__ var,
                                                        float* __restrict__ out_flat,
                                                        float* __restrict__ out_pad) {
    int o0 = blockIdx.y << 3;
    int p = blockIdx.x * 256 + threadIdx.x;
    int h = p >> 7, w = p & 127;
    float acc[8] = {};
    const float* ib0 = inpad + h * 130 + w;
    for (int c = 0; c < 256; ++c) {
        const float* ib = ib0 + (size_t)c * PS;
        float a00 = ib[0],   a01 = ib[1],   a02 = ib[2];
        float a10 = ib[130], a11 = ib[131], a12 = ib[132];
        float a20 = ib[260], a21 = ib[261], a22 = ib[262];
#pragma unroll
        for (int j = 0; j < 8; ++j) {
            const float* wc = wgt + ((size_t)(o0 + j) * 256 + c) * 9;
            acc[j] += a00 * wc[0] + a01 * wc[1] + a02 * wc[2]
                    + a10 * wc[3] + a11 * wc[4] + a12 * wc[5]
                    + a20 * wc[6] + a21 * wc[7] + a22 * wc[8];
        }
    }
#pragma unroll
    for (int j = 0; j < 8; ++j) {
        int o = o0 + j;
        float sc = gamma[o] * rsqrtf(var[o] + 1e-5f);
        float bi = beta[o] - mean[o] * sc;
        float r = fmaxf(acc[j] * sc + bi, 0.0f);
        if (out_flat) out_flat[(size_t)o * HW + p] = r;
        if (out_pad)  out_pad[(size_t)o * PS + (h + 1) * 130 + (w + 1)] = r;
    }
}

extern "C" void kernel_launch(void* const* d_in, const int* in_sizes, int n_in,
                              void* d_out, int out_size, void* d_ws, size_t ws_size,
                              hipStream_t stream) {
    const float* x     = (const float*)d_in[0];
    const float* llf   = (const float*)d_in[1];
    const float* fm_w  = (const float*)d_in[2];
    const float* fs_w  = (const float*)d_in[3];
    const float* p_w   = (const float*)d_in[4];
    const float* p_b   = (const float*)d_in[5];
    const float* dc_w  = (const float*)d_in[6];
    const float* lc1_w = (const float*)d_in[7];
    const float* bn1g  = (const float*)d_in[8];
    const float* bn1b  = (const float*)d_in[9];
    const float* bn1m  = (const float*)d_in[10];
    const float* bn1v  = (const float*)d_in[11];
    const float* lc2_w = (const float*)d_in[12];
    const float* bn2g  = (const float*)d_in[13];
    const float* bn2b  = (const float*)d_in[14];
    const float* bn2m  = (const float*)d_in[15];
    const float* bn2v  = (const float*)d_in[16];
    float* out1 = (float*)d_out;
    float* out2 = out1 + (size_t)256 * HW;

    if (ws_size < 79839232u) return;  // workspace layout below needs ~80 MB
    char* ws = (char*)d_ws;
    float*  ccpad = (float*) (ws);                 // 34,611,200 B
    float*  offb  = (float*) (ws + 34611200);      //  1,179,648 B
    int4*   IDX   = (int4*)  (ws + 35790848);      //  2,359,296 B
    float4* WT    = (float4*)(ws + 38150144);      //  2,359,296 B
    float*  dcwT  = (float*) (ws + 40509440);      //  4,718,592 B
    float*  bufA  = (float*) (ws + 45228032);      // 17,305,600 B (v flat, then fampad)
    float*  bufB  = (float*) (ws + 62533632);      // 17,305,600 B (u flat, then up1pad)

    // Cf ring must be zero before off_conv / fam_gemm read ccpad ch 256..511.
    zero_ring_k<<<dim3(516), 256, 0, stream>>>(ccpad + (size_t)256 * PS, 256);
    upsample_k<<<dim3(67, 256), 256, 0, stream>>>(x, ccpad);
    gemm1x1_sig_k<<<dim3(16, 32), 256, 0, stream>>>(fm_w, llf, bufA);                     // v (flat)
    u_matmul_k<<<dim3(2, 256), 256, 0, stream>>>(llf, bufA, bufB);                        // u (flat)
    gemm1x1_pad_k<<<dim3(16, 32), 256, 0, stream>>>(fs_w, bufB, ccpad + (size_t)256 * PS); // Cf
    // v and u are dead now: safe to convert bufA/bufB to padded planes.
    // (Round-1 bug: rings were zeroed BEFORE the flat v/u writes clobbered them.)
    zero_ring_k<<<dim3(516), 256, 0, stream>>>(bufA, 256);                                // fampad ring
    zero_ring_k<<<dim3(516), 256, 0, stream>>>(bufB, 256);                                // up1pad ring
    off_conv_k<<<dim3(64, 18), 256, 0, stream>>>(ccpad, p_w, offb);
    make_idx_k<<<dim3(576), 256, 0, stream>>>(offb, p_b, IDX, WT);
    transpose_dcw_k<<<dim3(4608), 256, 0, stream>>>(dc_w, dcwT);
    fam_gemm_k<<<dim3(128, 4), 256, 0, stream>>>(ccpad, dcwT, IDX, WT, bufA);             // fampad
    conv3x3_bnrelu_k<<<dim3(64, 32), 256, 0, stream>>>(bufA, lc1_w, bn1g, bn1b, bn1m, bn1v,
                                                       out1, bufB);                        // up1
    conv3x3_bnrelu_k<<<dim3(64, 32), 256, 0, stream>>>(bufB, lc2_w, bn2g, bn2b, bn2m, bn2v,
                                                       out2, nullptr);                     // up2
}

// Round 3
// 1409.438 us; speedup vs baseline: 1.8385x; 1.8385x over previous
//
#include <hip/hip_runtime.h>
#include <math.h>

#define HW   16384           // 128*128
#define PS   16900           // 130*130 f32 padded plane
#define PSH  17160           // 130*132 bf16 padded plane (stride 132)
#define SH   132

typedef __attribute__((ext_vector_type(8))) short bf16x8;
typedef __attribute__((ext_vector_type(4))) float f32x4;

__device__ inline unsigned short f2bf(float x) {
    unsigned int u = __float_as_uint(x);
    unsigned int r = (u + 0x7fffu + ((u >> 16) & 1u)) >> 16;
    return (unsigned short)r;
}
__device__ inline float bf2f(unsigned short h) {
    return __uint_as_float(((unsigned int)h) << 16);
}

// ---- zero the pad ring of nch f32 padded planes (stride 130) ---------------
__global__ __launch_bounds__(256) void zero_ring_k(float* __restrict__ base, int nch) {
    int t = blockIdx.x * 256 + threadIdx.x;
    if (t >= nch * 516) return;
    int ch = t / 516, rp = t - ch * 516;
    int row, col;
    if (rp < 130)      { row = 0;   col = rp; }
    else if (rp < 260) { row = 129; col = rp - 130; }
    else { int rem = rp - 260; row = 1 + (rem >> 1); col = (rem & 1) ? 129 : 0; }
    base[(size_t)ch * PS + row * 130 + col] = 0.0f;
}

// ---- zero the pad ring of nch bf16 padded planes (stride 132) --------------
__global__ __launch_bounds__(256) void zero_ring_h_k(unsigned short* __restrict__ base, int nch) {
    int t = blockIdx.x * 256 + threadIdx.x;
    if (t >= nch * 520) return;
    int ch = t / 520, rp = t - ch * 520;
    int row, col;
    if (rp < 132)      { row = 0;   col = rp; }
    else if (rp < 264) { row = 129; col = rp - 132; }
    else { int rem = rp - 264; row = 1 + (rem >> 1); col = (rem & 1) ? 129 : 0; }
    base[(size_t)ch * PSH + row * SH + col] = 0;
}

// ---- bilinear upsample (align_corners) 32x32 -> 128x128, into padded cc ----
__global__ __launch_bounds__(256) void upsample_k(const float* __restrict__ x,
                                                  float* __restrict__ ccpad) {
    int c = blockIdx.y;
    int idx = blockIdx.x * 256 + threadIdx.x;
    if (idx >= PS) return;
    int r = idx / 130, s = idx - r * 130;
    float val = 0.0f;
    if (r >= 1 && r <= 128 && s >= 1 && s <= 128) {
        int i = r - 1, j = s - 1;
        float yf = (float)i * (31.0f / 127.0f);
        float xf = (float)j * (31.0f / 127.0f);
        int y0 = min((int)yf, 31); int y1 = min(y0 + 1, 31);
        int x0 = min((int)xf, 31); int x1 = min(x0 + 1, 31);
        float wy = yf - (float)y0, wx = xf - (float)x0;
        const float* xc = x + (size_t)c * 1024;
        float a = xc[y0 * 32 + x0] * (1.0f - wx) + xc[y0 * 32 + x1] * wx;
        float b = xc[y1 * 32 + x0] * (1.0f - wx) + xc[y1 * 32 + x1] * wx;
        val = a * (1.0f - wy) + b * wy;
    }
    ccpad[(size_t)c * PS + idx] = val;
}

// ---- 1x1 conv GEMM + sigmoid ----------------------------------------------
__global__ __launch_bounds__(256) void gemm1x1_sig_k(const float* __restrict__ wmat,
                                                     const float* __restrict__ in,
                                                     float* __restrict__ out) {
    __shared__ float wl[2048];
    int tid = threadIdx.x;
    int o0 = blockIdx.y << 3;
    for (int i = tid; i < 2048; i += 256) wl[i] = wmat[(o0 << 8) + i];
    __syncthreads();
    int p = (blockIdx.x << 10) + (tid << 2);
    float4 acc[8];
#pragma unroll
    for (int j = 0; j < 8; ++j) acc[j] = make_float4(0.f, 0.f, 0.f, 0.f);
    for (int c = 0; c < 256; ++c) {
        float4 z = *(const float4*)(in + (size_t)c * HW + p);
#pragma unroll
        for (int j = 0; j < 8; ++j) {
            float wj = wl[(j << 8) + c];
            acc[j].x += wj * z.x; acc[j].y += wj * z.y;
            acc[j].z += wj * z.z; acc[j].w += wj * z.w;
        }
    }
#pragma unroll
    for (int j = 0; j < 8; ++j) {
        float4 r;
        r.x = 1.0f / (1.0f + expf(-acc[j].x));
        r.y = 1.0f / (1.0f + expf(-acc[j].y));
        r.z = 1.0f / (1.0f + expf(-acc[j].z));
        r.w = 1.0f / (1.0f + expf(-acc[j].w));
        *(float4*)(out + (size_t)(o0 + j) * HW + p) = r;
    }
}

// ---- 1x1 conv GEMM, writes into f32 padded planes (Cf -> ccpad hi) ---------
__global__ __launch_bounds__(256) void gemm1x1_pad_k(const float* __restrict__ wmat,
                                                     const float* __restrict__ in,
                                                     float* __restrict__ outpad) {
    __shared__ float wl[2048];
    int tid = threadIdx.x;
    int o0 = blockIdx.y << 3;
    for (int i = tid; i < 2048; i += 256) wl[i] = wmat[(o0 << 8) + i];
    __syncthreads();
    int p = (blockIdx.x << 10) + (tid << 2);
    float4 acc[8];
#pragma unroll
    for (int j = 0; j < 8; ++j) acc[j] = make_float4(0.f, 0.f, 0.f, 0.f);
    for (int c = 0; c < 256; ++c) {
        float4 z = *(const float4*)(in + (size_t)c * HW + p);
#pragma unroll
        for (int j = 0; j < 8; ++j) {
            float wj = wl[(j << 8) + c];
            acc[j].x += wj * z.x; acc[j].y += wj * z.y;
            acc[j].z += wj * z.z; acc[j].w += wj * z.w;
        }
    }
    int h = p >> 7, w = p & 127;
#pragma unroll
    for (int j = 0; j < 8; ++j) {
        float* dst = outpad + (size_t)(o0 + j) * PS + (h + 1) * 130 + (w + 1);
        dst[0] = acc[j].x; dst[1] = acc[j].y; dst[2] = acc[j].z; dst[3] = acc[j].w;
    }
}

// ---- u[c,h,w] = sum_k L[c,h,k]*v[c,k,w] + L[c,h,w] -------------------------
__global__ __launch_bounds__(256) void u_matmul_k(const float* __restrict__ llf,
                                                  const float* __restrict__ v,
                                                  float* __restrict__ u) {
    int c = blockIdx.y;
    const float* L = llf + (size_t)c * HW;
    const float* V = v   + (size_t)c * HW;
    float*       U = u   + (size_t)c * HW;
    int tid = threadIdx.x;
    int ty = tid >> 4, tx = tid & 15;
    int r0 = (blockIdx.x << 6) + (ty << 2);
    int w0 = tx << 3;
    float acc[4][8] = {};
    for (int k = 0; k < 128; ++k) {
        float a[4];
#pragma unroll
        for (int i = 0; i < 4; ++i) a[i] = L[(r0 + i) * 128 + k];
        float4 b0 = *(const float4*)(V + k * 128 + w0);
        float4 b1 = *(const float4*)(V + k * 128 + w0 + 4);
        float bv[8] = {b0.x, b0.y, b0.z, b0.w, b1.x, b1.y, b1.z, b1.w};
#pragma unroll
        for (int i = 0; i < 4; ++i)
#pragma unroll
            for (int j = 0; j < 8; ++j) acc[i][j] += a[i] * bv[j];
    }
#pragma unroll
    for (int i = 0; i < 4; ++i) {
#pragma unroll
        for (int j = 0; j < 8; ++j) acc[i][j] += L[(r0 + i) * 128 + w0 + j];
        *(float4*)(U + (r0 + i) * 128 + w0)     = make_float4(acc[i][0], acc[i][1], acc[i][2], acc[i][3]);
        *(float4*)(U + (r0 + i) * 128 + w0 + 4) = make_float4(acc[i][4], acc[i][5], acc[i][6], acc[i][7]);
    }
}

// ---- convert 512 f32 padded planes (stride 130) -> bf16 planes (stride 132)
__global__ __launch_bounds__(256) void cvt_bf16_k(const float* __restrict__ src,
                                                  unsigned short* __restrict__ dst) {
    int t = blockIdx.x * 256 + threadIdx.x;   // 512*16900 = 8,652,800 exactly
    int c = t / PS, r = t - c * PS;
    int row = r / 130, col = r - row * 130;
    dst[(size_t)c * PSH + row * SH + col] = f2bf(src[t]);
}

// ---- weights (O,C,3,3) f32 -> [k][o][c] bf16 (O=256) -----------------------
__global__ __launch_bounds__(256) void tr_ocK_k(const float* __restrict__ w,
                                                unsigned short* __restrict__ dst, int C) {
    int t = blockIdx.x * 256 + threadIdx.x;
    if (t >= 9 * 256 * C) return;
    int c = t % C; int rest = t / C; int o = rest & 255; int k = rest >> 8;
    dst[t] = f2bf(w[(size_t)o * C * 9 + c * 9 + k]);
}

// ---- p_w (18,512,3,3) f32 -> [k][32][512] bf16, zero-padded to 32 o --------
__global__ __launch_bounds__(256) void tr_pw_k(const float* __restrict__ w,
                                               unsigned short* __restrict__ dst) {
    int t = blockIdx.x * 256 + threadIdx.x;
    if (t >= 9 * 32 * 512) return;
    int c = t & 511; int rest = t >> 9; int o = rest & 31; int k = rest >> 5;
    dst[t] = (o < 18) ? f2bf(w[(size_t)o * 4608 + c * 9 + k]) : (unsigned short)0;
}

// ---- per-(pixel,k): 4 gather indices (stride-132 bf16 plane) + weights -----
__global__ __launch_bounds__(256) void make_idx_k(const float* __restrict__ offb,
                                                  const float* __restrict__ pb,
                                                  int4* __restrict__ IDX,
                                                  float4* __restrict__ WT) {
    int t = blockIdx.x * 256 + threadIdx.x;
    if (t >= 9 * HW) return;
    int k = t >> 14, p = t & 16383;
    int h = p >> 7, w = p & 127;
    float px = offb[(size_t)k * HW + p]       + pb[k]     + (float)(k / 3 - 1) + (float)(h + 1);
    float py = offb[(size_t)(9 + k) * HW + p] + pb[9 + k] + (float)(k % 3 - 1) + (float)(w + 1);
    float fx = floorf(px), fy = floorf(py);
    float x0 = fminf(fmaxf(fx,        0.f), 129.f);
    float x1 = fminf(fmaxf(fx + 1.0f, 0.f), 129.f);
    float y0 = fminf(fmaxf(fy,        0.f), 129.f);
    float y1 = fminf(fmaxf(fy + 1.0f, 0.f), 129.f);
    float pxc = fminf(fmaxf(px, 0.f), 129.f);
    float pyc = fminf(fmaxf(py, 0.f), 129.f);
    float gx0 = 1.0f + x0 - pxc, gx1 = 1.0f - x1 + pxc;
    float gy0 = 1.0f + y0 - pyc, gy1 = 1.0f - y1 + pyc;
    int ix0 = (int)x0, ix1 = (int)x1, iy0 = (int)y0, iy1 = (int)y1;
    IDX[t] = make_int4(ix0 * SH + iy0, ix1 * SH + iy1, ix0 * SH + iy1, ix1 * SH + iy0);
    WT[t]  = make_float4(gx0 * gy0, gx1 * gy1, gx0 * gy1, gx1 * gy0);
}

// ============ deformable contraction, bf16 MFMA =============================
// D[o,px] = sum_{k,c} w[k][o][c] * bilinear(cc[c]; k,px) ; +Cf in epilogue.
// Tile 128 o x 128 px; grid 256 1-D, swizzled so each XCD owns 16 hrows.
__global__ __launch_bounds__(256, 1) void fam_mfma_k(
        const unsigned short* __restrict__ cch,    // 512 bf16 planes PSH
        const unsigned short* __restrict__ dcwTh,  // [9][256][512] bf16
        const int4* __restrict__ IDX, const float4* __restrict__ WT,
        unsigned short* __restrict__ famh) {       // 256 bf16 planes PSH
    __shared__ __align__(16) unsigned short Bs[128][40];   // [px][c-chunk], pad->40
    int b = blockIdx.x;
    int xcd = b & 7, slot = b >> 3;
    int otile = slot & 1;
    int hrow = (xcd << 4) + (slot >> 1);   // XCD-band: 16 contiguous rows/XCD
    int o0 = otile << 7;
    int tid = threadIdx.x;
    int wv = tid >> 6, lane = tid & 63;
    int wr = wv >> 1, wc = wv & 1;         // wave quadrant (64x64)
    int lr = lane & 15, lg = lane >> 4;
    int px = tid & 127, sg = tid >> 7;     // staging: own pixel, 16 cc each
    f32x4 acc[4][4];
#pragma unroll
    for (int i = 0; i < 4; ++i)
#pragma unroll
        for (int j = 0; j < 4; ++j) acc[i][j] = (f32x4){0.f, 0.f, 0.f, 0.f};

    for (int kt = 0; kt < 9; ++kt) {
        int4   id = IDX[(kt << 14) + (hrow << 7) + px];
        float4 wt = WT [(kt << 14) + (hrow << 7) + px];
        const unsigned short* dwk = dcwTh + (size_t)kt * 131072 + (size_t)o0 * 512;
        for (int ks = 0; ks < 512; ks += 32) {
            __syncthreads();
            // stage B: bilinear gather, bf16 in/out, f32 weighting
#pragma unroll
            for (int q = 0; q < 4; ++q) {
                unsigned short pk[4];
#pragma unroll
                for (int e = 0; e < 4; ++e) {
                    int cc = (sg << 4) + (q << 2) + e;
                    const unsigned short* cb = cch + (size_t)(ks + cc) * PSH;
                    float val = wt.x * bf2f(cb[id.x]) + wt.y * bf2f(cb[id.y])
                              + wt.z * bf2f(cb[id.z]) + wt.w * bf2f(cb[id.w]);
                    pk[e] = f2bf(val);
                }
                *(short4*)&Bs[px][(sg << 4) + (q << 2)] = *(short4*)pk;
            }
            __syncthreads();
            // A frags straight from global (L2-resident weights), B from LDS
            bf16x8 af[4], bfr[4];
#pragma unroll
            for (int mi = 0; mi < 4; ++mi) {
                int o = (wr << 6) + (mi << 4) + lr;
                af[mi] = *(const bf16x8*)(dwk + (size_t)o * 512 + ks + (lg << 3));
            }
#pragma unroll
            for (int ni = 0; ni < 4; ++ni) {
                int n = (wc << 6) + (ni << 4) + lr;
                bfr[ni] = *(const bf16x8*)(&Bs[n][lg << 3]);
            }
#pragma unroll
            for (int mi = 0; mi < 4; ++mi)
#pragma unroll
                for (int ni = 0; ni < 4; ++ni)
                    acc[mi][ni] = __builtin_amdgcn_mfma_f32_16x16x32_bf16(
                        af[mi], bfr[ni], acc[mi][ni], 0, 0, 0);
        }
    }
    // epilogue: + Cf (bf16 planes 256..511) -> famh padded bf16
    size_t rowb = (size_t)(hrow + 1) * SH;
#pragma unroll
    for (int mi = 0; mi < 4; ++mi) {
#pragma unroll
        for (int ni = 0; ni < 4; ++ni) {
#pragma unroll
            for (int r = 0; r < 4; ++r) {
                int o   = o0 + (wr << 6) + (mi << 4) + (lg << 2) + r;
                int pxx = (wc << 6) + (ni << 4) + lr;
                float cf = bf2f(cch[(size_t)(256 + o) * PSH + rowb + pxx + 1]);
                famh[(size_t)o * PSH + rowb + pxx + 1] = f2bf(acc[mi][ni][r] + cf);
            }
        }
    }
}

// ============ 3x3 conv 256->256 bf16 MFMA + BN + ReLU =======================
__global__ __launch_bounds__(256, 1) void conv_mfma_k(
        const unsigned short* __restrict__ inh,   // 256 bf16 planes PSH, ring=0
        const unsigned short* __restrict__ wTh,   // [9][256][256] bf16
        const float* __restrict__ gam, const float* __restrict__ bet,
        const float* __restrict__ mean, const float* __restrict__ var,
        float* __restrict__ out_flat,             // [256][HW] f32
        unsigned short* __restrict__ out_padh) {  // optional bf16 planes
    __shared__ __align__(16) unsigned short Bs[128][40];
    __shared__ float scs[128], bis[128];
    int b = blockIdx.x;
    int xcd = b & 7, slot = b >> 3;
    int otile = slot & 1;
    int hrow = (xcd << 4) + (slot >> 1);
    int o0 = otile << 7;
    int tid = threadIdx.x;
    int wv = tid >> 6, lane = tid & 63;
    int wr = wv >> 1, wc = wv & 1;
    int lr = lane & 15, lg = lane >> 4;
    int px = tid & 127, sg = tid >> 7;
    if (tid < 128) {
        int o = o0 + tid;
        float sc = gam[o] * rsqrtf(var[o] + 1e-5f);
        scs[tid] = sc;
        bis[tid] = bet[o] - mean[o] * sc;
    }
    f32x4 acc[4][4];
#pragma unroll
    for (int i = 0; i < 4; ++i)
#pragma unroll
        for (int j = 0; j < 4; ++j) acc[i][j] = (f32x4){0.f, 0.f, 0.f, 0.f};

    for (int kt = 0; kt < 9; ++kt) {
        int dy = kt / 3 - 1, dx = kt % 3 - 1;
        const unsigned short* wk  = wTh + (size_t)kt * 65536 + (size_t)o0 * 256;
        const unsigned short* src = inh + (size_t)(hrow + dy + 1) * SH + (px + dx + 1);
        for (int ks = 0; ks < 256; ks += 32) {
            __syncthreads();
#pragma unroll
            for (int q = 0; q < 4; ++q) {
                unsigned short pk[4];
#pragma unroll
                for (int e = 0; e < 4; ++e) {
                    int cc = (sg << 4) + (q << 2) + e;
                    pk[e] = src[(size_t)(ks + cc) * PSH];
                }
                *(short4*)&Bs[px][(sg << 4) + (q << 2)] = *(short4*)pk;
            }
            __syncthreads();
            bf16x8 af[4], bfr[4];
#pragma unroll
            for (int mi = 0; mi < 4; ++mi) {
                int o = (wr << 6) + (mi << 4) + lr;
                af[mi] = *(const bf16x8*)(wk + (size_t)o * 256 + ks + (lg << 3));
            }
#pragma unroll
            for (int ni = 0; ni < 4; ++ni) {
                int n = (wc << 6) + (ni << 4) + lr;
                bfr[ni] = *(const bf16x8*)(&Bs[n][lg << 3]);
            }
#pragma unroll
            for (int mi = 0; mi < 4; ++mi)
#pragma unroll
                for (int ni = 0; ni < 4; ++ni)
                    acc[mi][ni] = __builtin_amdgcn_mfma_f32_16x16x32_bf16(
                        af[mi], bfr[ni], acc[mi][ni], 0, 0, 0);
        }
    }
    size_t rowb = (size_t)(hrow + 1) * SH;
#pragma unroll
    for (int mi = 0; mi < 4; ++mi) {
#pragma unroll
        for (int ni = 0; ni < 4; ++ni) {
#pragma unroll
            for (int r = 0; r < 4; ++r) {
                int ol  = (wr << 6) + (mi << 4) + (lg << 2) + r;
                int o   = o0 + ol;
                int pxx = (wc << 6) + (ni << 4) + lr;
                float rv = fmaxf(acc[mi][ni][r] * scs[ol] + bis[ol], 0.0f);
                out_flat[(size_t)o * HW + (hrow << 7) + pxx] = rv;
                if (out_padh)
                    out_padh[(size_t)o * PSH + rowb + pxx + 1] = f2bf(rv);
            }
        }
    }
}

// ============ offset conv 512->18 (padded to 32) bf16 MFMA ==================
__global__ __launch_bounds__(256, 1) void off_mfma_k(
        const unsigned short* __restrict__ cch,   // 512 bf16 planes PSH
        const unsigned short* __restrict__ pwTh,  // [9][32][512] bf16
        float* __restrict__ offb) {               // [18][HW] f32
    __shared__ __align__(16) unsigned short Bs[128][40];
    int b = blockIdx.x;                 // 128 blocks
    int xcd = b & 7, slot = b >> 3;
    int hrow = (xcd << 4) + slot;
    int tid = threadIdx.x;
    int wv = tid >> 6, lane = tid & 63;
    int wr = wv >> 1, wc = wv & 1;      // wr: o-half (16), wc: px-half (64)
    int lr = lane & 15, lg = lane >> 4;
    int px = tid & 127, sg = tid >> 7;
    f32x4 acc[4];
#pragma unroll
    for (int j = 0; j < 4; ++j) acc[j] = (f32x4){0.f, 0.f, 0.f, 0.f};

    for (int kt = 0; kt < 9; ++kt) {
        int dy = kt / 3 - 1, dx = kt % 3 - 1;
        const unsigned short* wk  = pwTh + (size_t)kt * 16384;
        const unsigned short* src = cch + (size_t)(hrow + dy + 1) * SH + (px + dx + 1);
        for (int ks = 0; ks < 512; ks += 32) {
            __syncthreads();
#pragma unroll
            for (int q = 0; q < 4; ++q) {
                unsigned short pk[4];
#pragma unroll
                for (int e = 0; e < 4; ++e) {
                    int cc = (sg << 4) + (q << 2) + e;
                    pk[e] = src[(size_t)(ks + cc) * PSH];
                }
                *(short4*)&Bs[px][(sg << 4) + (q << 2)] = *(short4*)pk;
            }
            __syncthreads();
            bf16x8 af, bfr[4];
            af = *(const bf16x8*)(wk + (size_t)((wr << 4) + lr) * 512 + ks + (lg << 3));
#pragma unroll
            for (int ni = 0; ni < 4; ++ni) {
                int n = (wc << 6) + (ni << 4) + lr;
                bfr[ni] = *(const bf16x8*)(&Bs[n][lg << 3]);
            }
#pragma unroll
            for (int ni = 0; ni < 4; ++ni)
                acc[ni] = __builtin_amdgcn_mfma_f32_16x16x32_bf16(af, bfr[ni], acc[ni], 0, 0, 0);
        }
    }
#pragma unroll
    for (int ni = 0; ni < 4; ++ni)
#pragma unroll
        for (int r = 0; r < 4; ++r) {
            int o = (wr << 4) + (lg << 2) + r;
            if (o < 18) {
                int pxx = (wc << 6) + (ni << 4) + lr;
                offb[(size_t)o * HW + (hrow << 7) + pxx] = acc[ni][r];
            }
        }
}

extern "C" void kernel_launch(void* const* d_in, const int* in_sizes, int n_in,
                              void* d_out, int out_size, void* d_ws, size_t ws_size,
                              hipStream_t stream) {
    const float* x     = (const float*)d_in[0];
    const float* llf   = (const float*)d_in[1];
    const float* fm_w  = (const float*)d_in[2];
    const float* fs_w  = (const float*)d_in[3];
    const float* p_w   = (const float*)d_in[4];
    const float* p_b   = (const float*)d_in[5];
    const float* dc_w  = (const float*)d_in[6];
    const float* lc1_w = (const float*)d_in[7];
    const float* bn1g  = (const float*)d_in[8];
    const float* bn1b  = (const float*)d_in[9];
    const float* bn1m  = (const float*)d_in[10];
    const float* bn1v  = (const float*)d_in[11];
    const float* lc2_w = (const float*)d_in[12];
    const float* bn2g  = (const float*)d_in[13];
    const float* bn2b  = (const float*)d_in[14];
    const float* bn2m  = (const float*)d_in[15];
    const float* bn2v  = (const float*)d_in[16];
    float* out1 = (float*)d_out;
    float* out2 = out1 + (size_t)256 * HW;

    if (ws_size < 68960256u) return;
    char* ws = (char*)d_ws;
    // R0 [0, 34,611,200): ccpad f32 (dead after cvt) -> famh @0, up1h @9,000,000
    float*          ccpad = (float*)ws;
    unsigned short* famh  = (unsigned short*)ws;
    unsigned short* up1h  = (unsigned short*)(ws + 9000000);
    // R1 [34,611,200, +17,571,840): v f32 (dead after u_matmul) -> ccpadh bf16
    float*          vbuf  = (float*)(ws + 34611200);
    unsigned short* cch   = (unsigned short*)(ws + 34611200);
    // R2 [52,183,040, +16,777,216): u f32 (dead after Cf) -> small tensors
    char* R2 = ws + 52183040;
    float*          ubuf   = (float*)R2;
    float*          offb   = (float*)R2;                        // 1,179,648
    int4*           IDX    = (int4*)  (R2 + 1179648);           // 2,359,296
    float4*         WT     = (float4*)(R2 + 3538944);           // 2,359,296
    unsigned short* dcwTh  = (unsigned short*)(R2 + 5898240);   // 2,359,296
    unsigned short* lcw1Th = (unsigned short*)(R2 + 8257536);   // 1,179,648
    unsigned short* lcw2Th = (unsigned short*)(R2 + 9437184);   // 1,179,648
    unsigned short* pwTh   = (unsigned short*)(R2 + 10616832);  //   294,912

    zero_ring_k<<<dim3(516), 256, 0, stream>>>(ccpad + (size_t)256 * PS, 256);
    upsample_k<<<dim3(67, 256), 256, 0, stream>>>(x, ccpad);
    gemm1x1_sig_k<<<dim3(16, 32), 256, 0, stream>>>(fm_w, llf, vbuf);
    u_matmul_k<<<dim3(2, 256), 256, 0, stream>>>(llf, vbuf, ubuf);
    gemm1x1_pad_k<<<dim3(16, 32), 256, 0, stream>>>(fs_w, ubuf, ccpad + (size_t)256 * PS);
    cvt_bf16_k<<<dim3(33800), 256, 0, stream>>>(ccpad, cch);            // v dead, u dead
    tr_ocK_k<<<dim3(4608), 256, 0, stream>>>(dc_w, dcwTh, 512);
    tr_ocK_k<<<dim3(2304), 256, 0, stream>>>(lc1_w, lcw1Th, 256);
    tr_ocK_k<<<dim3(2304), 256, 0, stream>>>(lc2_w, lcw2Th, 256);
    tr_pw_k<<<dim3(576), 256, 0, stream>>>(p_w, pwTh);
    off_mfma_k<<<dim3(128), 256, 0, stream>>>(cch, pwTh, offb);
    make_idx_k<<<dim3(576), 256, 0, stream>>>(offb, p_b, IDX, WT);
    zero_ring_h_k<<<dim3(521), 256, 0, stream>>>(famh, 256);            // ccpad f32 dead now
    zero_ring_h_k<<<dim3(521), 256, 0, stream>>>(up1h, 256);
    fam_mfma_k<<<dim3(256), 256, 0, stream>>>(cch, dcwTh, IDX, WT, famh);
    conv_mfma_k<<<dim3(256), 256, 0, stream>>>(famh, lcw1Th, bn1g, bn1b, bn1m, bn1v,
                                               out1, up1h);
    conv_mfma_k<<<dim3(256), 256, 0, stream>>>(up1h, lcw2Th, bn2g, bn2b, bn2m, bn2v,
                                               out2, nullptr);
}

// Round 4
// 879.553 us; speedup vs baseline: 2.9461x; 1.6024x over previous
//
#include <hip/hip_runtime.h>
#include <math.h>

#define HW   16384           // 128*128
#define PS   16900           // 130*130 f32 padded plane
#define PSH  17160           // 130*132 bf16 padded plane (stride 132)
#define SH   132

typedef __attribute__((ext_vector_type(8))) short bf16x8;
typedef __attribute__((ext_vector_type(4))) float f32x4;

__device__ inline unsigned short f2bf(float x) {
    unsigned int u = __float_as_uint(x);
    unsigned int r = (u + 0x7fffu + ((u >> 16) & 1u)) >> 16;
    return (unsigned short)r;
}
__device__ inline float bf2f(unsigned short h) {
    return __uint_as_float(((unsigned int)h) << 16);
}

// ---- zero the pad ring of nch f32 padded planes (stride 130) ---------------
__global__ __launch_bounds__(256) void zero_ring_k(float* __restrict__ base, int nch) {
    int t = blockIdx.x * 256 + threadIdx.x;
    if (t >= nch * 516) return;
    int ch = t / 516, rp = t - ch * 516;
    int row, col;
    if (rp < 130)      { row = 0;   col = rp; }
    else if (rp < 260) { row = 129; col = rp - 130; }
    else { int rem = rp - 260; row = 1 + (rem >> 1); col = (rem & 1) ? 129 : 0; }
    base[(size_t)ch * PS + row * 130 + col] = 0.0f;
}

// ---- zero the pad ring of nch bf16 padded planes (stride 132) --------------
__global__ __launch_bounds__(256) void zero_ring_h_k(unsigned short* __restrict__ base, int nch) {
    int t = blockIdx.x * 256 + threadIdx.x;
    if (t >= nch * 520) return;
    int ch = t / 520, rp = t - ch * 520;
    int row, col;
    if (rp < 132)      { row = 0;   col = rp; }
    else if (rp < 264) { row = 129; col = rp - 132; }
    else { int rem = rp - 264; row = 1 + (rem >> 1); col = (rem & 1) ? 129 : 0; }
    base[(size_t)ch * PSH + row * SH + col] = 0;
}

// ---- bilinear upsample (align_corners) 32x32 -> 128x128, into padded cc ----
__global__ __launch_bounds__(256) void upsample_k(const float* __restrict__ x,
                                                  float* __restrict__ ccpad) {
    int c = blockIdx.y;
    int idx = blockIdx.x * 256 + threadIdx.x;
    if (idx >= PS) return;
    int r = idx / 130, s = idx - r * 130;
    float val = 0.0f;
    if (r >= 1 && r <= 128 && s >= 1 && s <= 128) {
        int i = r - 1, j = s - 1;
        float yf = (float)i * (31.0f / 127.0f);
        float xf = (float)j * (31.0f / 127.0f);
        int y0 = min((int)yf, 31); int y1 = min(y0 + 1, 31);
        int x0 = min((int)xf, 31); int x1 = min(x0 + 1, 31);
        float wy = yf - (float)y0, wx = xf - (float)x0;
        const float* xc = x + (size_t)c * 1024;
        float a = xc[y0 * 32 + x0] * (1.0f - wx) + xc[y0 * 32 + x1] * wx;
        float b = xc[y1 * 32 + x0] * (1.0f - wx) + xc[y1 * 32 + x1] * wx;
        val = a * (1.0f - wy) + b * wy;
    }
    ccpad[(size_t)c * PS + idx] = val;
}

// ---- 1x1 conv GEMM + sigmoid ----------------------------------------------
__global__ __launch_bounds__(256) void gemm1x1_sig_k(const float* __restrict__ wmat,
                                                     const float* __restrict__ in,
                                                     float* __restrict__ out) {
    __shared__ float wl[2048];
    int tid = threadIdx.x;
    int o0 = blockIdx.y << 3;
    for (int i = tid; i < 2048; i += 256) wl[i] = wmat[(o0 << 8) + i];
    __syncthreads();
    int p = (blockIdx.x << 10) + (tid << 2);
    float4 acc[8];
#pragma unroll
    for (int j = 0; j < 8; ++j) acc[j] = make_float4(0.f, 0.f, 0.f, 0.f);
    for (int c = 0; c < 256; ++c) {
        float4 z = *(const float4*)(in + (size_t)c * HW + p);
#pragma unroll
        for (int j = 0; j < 8; ++j) {
            float wj = wl[(j << 8) + c];
            acc[j].x += wj * z.x; acc[j].y += wj * z.y;
            acc[j].z += wj * z.z; acc[j].w += wj * z.w;
        }
    }
#pragma unroll
    for (int j = 0; j < 8; ++j) {
        float4 r;
        r.x = 1.0f / (1.0f + expf(-acc[j].x));
        r.y = 1.0f / (1.0f + expf(-acc[j].y));
        r.z = 1.0f / (1.0f + expf(-acc[j].z));
        r.w = 1.0f / (1.0f + expf(-acc[j].w));
        *(float4*)(out + (size_t)(o0 + j) * HW + p) = r;
    }
}

// ---- 1x1 conv GEMM, writes into f32 padded planes (Cf -> ccpad hi) ---------
__global__ __launch_bounds__(256) void gemm1x1_pad_k(const float* __restrict__ wmat,
                                                     const float* __restrict__ in,
                                                     float* __restrict__ outpad) {
    __shared__ float wl[2048];
    int tid = threadIdx.x;
    int o0 = blockIdx.y << 3;
    for (int i = tid; i < 2048; i += 256) wl[i] = wmat[(o0 << 8) + i];
    __syncthreads();
    int p = (blockIdx.x << 10) + (tid << 2);
    float4 acc[8];
#pragma unroll
    for (int j = 0; j < 8; ++j) acc[j] = make_float4(0.f, 0.f, 0.f, 0.f);
    for (int c = 0; c < 256; ++c) {
        float4 z = *(const float4*)(in + (size_t)c * HW + p);
#pragma unroll
        for (int j = 0; j < 8; ++j) {
            float wj = wl[(j << 8) + c];
            acc[j].x += wj * z.x; acc[j].y += wj * z.y;
            acc[j].z += wj * z.z; acc[j].w += wj * z.w;
        }
    }
    int h = p >> 7, w = p & 127;
#pragma unroll
    for (int j = 0; j < 8; ++j) {
        float* dst = outpad + (size_t)(o0 + j) * PS + (h + 1) * 130 + (w + 1);
        dst[0] = acc[j].x; dst[1] = acc[j].y; dst[2] = acc[j].z; dst[3] = acc[j].w;
    }
}

// ---- u[c,h,w] = sum_k L[c,h,k]*v[c,k,w] + L[c,h,w] -------------------------
__global__ __launch_bounds__(256) void u_matmul_k(const float* __restrict__ llf,
                                                  const float* __restrict__ v,
                                                  float* __restrict__ u) {
    int c = blockIdx.y;
    const float* L = llf + (size_t)c * HW;
    const float* V = v   + (size_t)c * HW;
    float*       U = u   + (size_t)c * HW;
    int tid = threadIdx.x;
    int ty = tid >> 4, tx = tid & 15;
    int r0 = (blockIdx.x << 6) + (ty << 2);
    int w0 = tx << 3;
    float acc[4][8] = {};
    for (int k = 0; k < 128; ++k) {
        float a[4];
#pragma unroll
        for (int i = 0; i < 4; ++i) a[i] = L[(r0 + i) * 128 + k];
        float4 b0 = *(const float4*)(V + k * 128 + w0);
        float4 b1 = *(const float4*)(V + k * 128 + w0 + 4);
        float bv[8] = {b0.x, b0.y, b0.z, b0.w, b1.x, b1.y, b1.z, b1.w};
#pragma unroll
        for (int i = 0; i < 4; ++i)
#pragma unroll
            for (int j = 0; j < 8; ++j) acc[i][j] += a[i] * bv[j];
    }
#pragma unroll
    for (int i = 0; i < 4; ++i) {
#pragma unroll
        for (int j = 0; j < 8; ++j) acc[i][j] += L[(r0 + i) * 128 + w0 + j];
        *(float4*)(U + (r0 + i) * 128 + w0)     = make_float4(acc[i][0], acc[i][1], acc[i][2], acc[i][3]);
        *(float4*)(U + (r0 + i) * 128 + w0 + 4) = make_float4(acc[i][4], acc[i][5], acc[i][6], acc[i][7]);
    }
}

// ---- convert 512 f32 padded planes (stride 130) -> bf16 planes (stride 132)
__global__ __launch_bounds__(256) void cvt_bf16_k(const float* __restrict__ src,
                                                  unsigned short* __restrict__ dst) {
    int t = blockIdx.x * 256 + threadIdx.x;   // 512*16900 = 8,652,800 exactly
    int c = t / PS, r = t - c * PS;
    int row = r / 130, col = r - row * 130;
    dst[(size_t)c * PSH + row * SH + col] = f2bf(src[t]);
}

// ---- weights (O,C,3,3) f32 -> [k][o][c] bf16 (O=256) -----------------------
__global__ __launch_bounds__(256) void tr_ocK_k(const float* __restrict__ w,
                                                unsigned short* __restrict__ dst, int C) {
    int t = blockIdx.x * 256 + threadIdx.x;
    if (t >= 9 * 256 * C) return;
    int c = t % C; int rest = t / C; int o = rest & 255; int k = rest >> 8;
    dst[t] = f2bf(w[(size_t)o * C * 9 + c * 9 + k]);
}

// ---- p_w (18,512,3,3) f32 -> [k][32][512] bf16, zero-padded to 32 o --------
__global__ __launch_bounds__(256) void tr_pw_k(const float* __restrict__ w,
                                               unsigned short* __restrict__ dst) {
    int t = blockIdx.x * 256 + threadIdx.x;
    if (t >= 9 * 32 * 512) return;
    int c = t & 511; int rest = t >> 9; int o = rest & 31; int k = rest >> 5;
    dst[t] = (o < 18) ? f2bf(w[(size_t)o * 4608 + c * 9 + k]) : (unsigned short)0;
}

// ============ offset conv 512->18: channel-split partials ===================
// grid 512: each block = 32o x 128px x 128ch partial -> pbuf[cg][32][HW] f32
__global__ __launch_bounds__(256, 2) void off_part_k(
        const unsigned short* __restrict__ cch,   // 512 bf16 planes PSH
        const unsigned short* __restrict__ pwTh,  // [9][32][512] bf16
        float* __restrict__ pbuf) {               // [4][32][HW] f32
    __shared__ __align__(16) unsigned short Bs[128][40];
    int b = blockIdx.x;
    int xcd = b & 7, slot = b >> 3;               // 64 slots
    int hrow = (xcd << 4) + (slot >> 2);
    int cg = slot & 3, c0 = cg << 7;
    int tid = threadIdx.x;
    int wv = tid >> 6, lane = tid & 63;
    int wr = wv >> 1, wc = wv & 1;                // o-half(16) x px-half(64)
    int lr = lane & 15, lg = lane >> 4;
    int px = tid & 127, sg = tid >> 7;
    f32x4 acc[4];
#pragma unroll
    for (int j = 0; j < 4; ++j) acc[j] = (f32x4){0.f, 0.f, 0.f, 0.f};

    for (int kt = 0; kt < 9; ++kt) {
        int dy = kt / 3 - 1, dx = kt % 3 - 1;
        const unsigned short* src = cch + (size_t)(hrow + dy + 1) * SH + (px + dx + 1);
        for (int ksl = 0; ksl < 128; ksl += 32) {
            __syncthreads();
#pragma unroll
            for (int q = 0; q < 4; ++q) {
                unsigned short pk[4];
#pragma unroll
                for (int e = 0; e < 4; ++e) {
                    int c = c0 + ksl + (sg << 4) + (q << 2) + e;
                    pk[e] = src[(size_t)c * PSH];
                }
                *(short4*)&Bs[px][(sg << 4) + (q << 2)] = *(short4*)pk;
            }
            __syncthreads();
            bf16x8 af, bfr[4];
            af = *(const bf16x8*)(pwTh + (size_t)kt * 16384
                                  + (size_t)((wr << 4) + lr) * 512 + c0 + ksl + (lg << 3));
#pragma unroll
            for (int ni = 0; ni < 4; ++ni) {
                int n = (wc << 6) + (ni << 4) + lr;
                bfr[ni] = *(const bf16x8*)(&Bs[n][lg << 3]);
            }
#pragma unroll
            for (int ni = 0; ni < 4; ++ni)
                acc[ni] = __builtin_amdgcn_mfma_f32_16x16x32_bf16(af, bfr[ni], acc[ni], 0, 0, 0);
        }
    }
#pragma unroll
    for (int ni = 0; ni < 4; ++ni)
#pragma unroll
        for (int r = 0; r < 4; ++r) {
            int o = (wr << 4) + (lg << 2) + r;
            int p = (hrow << 7) + (wc << 6) + (ni << 4) + lr;
            pbuf[(size_t)((cg << 5) + o) * HW + p] = acc[ni][r];
        }
}

// ---- per-(pixel,k): sum 4 partials, 4 gather indices + bilinear weights ----
__global__ __launch_bounds__(256) void make_idx_k(const float* __restrict__ pbuf,
                                                  const float* __restrict__ pb,
                                                  int4* __restrict__ IDX,
                                                  float4* __restrict__ WT) {
    int t = blockIdx.x * 256 + threadIdx.x;
    if (t >= 9 * HW) return;
    int k = t >> 14, p = t & 16383;
    int h = p >> 7, w = p & 127;
    float ox = 0.f, oy = 0.f;
#pragma unroll
    for (int cg = 0; cg < 4; ++cg) {
        ox += pbuf[(size_t)((cg << 5) + k) * HW + p];
        oy += pbuf[(size_t)((cg << 5) + 9 + k) * HW + p];
    }
    float px = ox + pb[k]     + (float)(k / 3 - 1) + (float)(h + 1);
    float py = oy + pb[9 + k] + (float)(k % 3 - 1) + (float)(w + 1);
    float fx = floorf(px), fy = floorf(py);
    float x0 = fminf(fmaxf(fx,        0.f), 129.f);
    float x1 = fminf(fmaxf(fx + 1.0f, 0.f), 129.f);
    float y0 = fminf(fmaxf(fy,        0.f), 129.f);
    float y1 = fminf(fmaxf(fy + 1.0f, 0.f), 129.f);
    float pxc = fminf(fmaxf(px, 0.f), 129.f);
    float pyc = fminf(fmaxf(py, 0.f), 129.f);
    float gx0 = 1.0f + x0 - pxc, gx1 = 1.0f - x1 + pxc;
    float gy0 = 1.0f + y0 - pyc, gy1 = 1.0f - y1 + pyc;
    int ix0 = (int)x0, ix1 = (int)x1, iy0 = (int)y0, iy1 = (int)y1;
    IDX[t] = make_int4(ix0 * SH + iy0, ix1 * SH + iy1, ix0 * SH + iy1, ix1 * SH + iy0);
    WT[t]  = make_float4(gx0 * gy0, gx1 * gy1, gx0 * gy1, gx1 * gy0);
}

// ============ deformable contraction: full-M 256o x 32px tiles ==============
// grid 512 (2 blocks/CU): no gather duplication across o-tiles.
__global__ __launch_bounds__(256, 2) void fam2_k(
        const unsigned short* __restrict__ cch,    // 512 bf16 planes PSH
        const unsigned short* __restrict__ dcwTh,  // [9][256][512] bf16
        const int4* __restrict__ IDX, const float4* __restrict__ WT,
        unsigned short* __restrict__ famh) {       // 256 bf16 planes PSH
    __shared__ __align__(16) unsigned short Bs[32][40];
    int b = blockIdx.x;
    int xcd = b & 7, slot = b >> 3;
    int nt = (xcd << 6) + slot;            // XCD owns 64 contiguous n-tiles
    int hrow = nt >> 2, pc0 = (nt & 3) << 5;
    int tid = threadIdx.x;
    int wv = tid >> 6, lane = tid & 63;
    int lr = lane & 15, lg = lane >> 4;
    int pxl = tid & 31, cg = tid >> 5;     // 8 c-groups of 4 channels
    int p = (hrow << 7) + pc0 + pxl;
    f32x4 acc[4][2];
#pragma unroll
    for (int i = 0; i < 4; ++i)
#pragma unroll
        for (int j = 0; j < 2; ++j) acc[i][j] = (f32x4){0.f, 0.f, 0.f, 0.f};

    for (int kt = 0; kt < 9; ++kt) {
        int4   id = IDX[(kt << 14) + p];
        float4 wt = WT [(kt << 14) + p];
        const unsigned short* dwk = dcwTh + (size_t)kt * 131072;
        for (int ks = 0; ks < 512; ks += 32) {
            __syncthreads();
            unsigned short pk[4];
#pragma unroll
            for (int e = 0; e < 4; ++e) {
                int c = ks + (cg << 2) + e;
                const unsigned short* cb = cch + (size_t)c * PSH;
                float val = wt.x * bf2f(cb[id.x]) + wt.y * bf2f(cb[id.y])
                          + wt.z * bf2f(cb[id.z]) + wt.w * bf2f(cb[id.w]);
                pk[e] = f2bf(val);
            }
            *(short4*)&Bs[pxl][cg << 2] = *(short4*)pk;
            __syncthreads();
            bf16x8 af[4], bfr[2];
#pragma unroll
            for (int mi = 0; mi < 4; ++mi) {
                int o = (wv << 6) + (mi << 4) + lr;
                af[mi] = *(const bf16x8*)(dwk + (size_t)o * 512 + ks + (lg << 3));
            }
#pragma unroll
            for (int ni = 0; ni < 2; ++ni) {
                int n = (ni << 4) + lr;
                bfr[ni] = *(const bf16x8*)(&Bs[n][lg << 3]);
            }
#pragma unroll
            for (int mi = 0; mi < 4; ++mi)
#pragma unroll
                for (int ni = 0; ni < 2; ++ni)
                    acc[mi][ni] = __builtin_amdgcn_mfma_f32_16x16x32_bf16(
                        af[mi], bfr[ni], acc[mi][ni], 0, 0, 0);
        }
    }
    size_t rowb = (size_t)(hrow + 1) * SH;
#pragma unroll
    for (int mi = 0; mi < 4; ++mi)
#pragma unroll
        for (int ni = 0; ni < 2; ++ni)
#pragma unroll
            for (int r = 0; r < 4; ++r) {
                int o   = (wv << 6) + (mi << 4) + (lg << 2) + r;
                int pxx = pc0 + (ni << 4) + lr;
                float cf = bf2f(cch[(size_t)(256 + o) * PSH + rowb + pxx + 1]);
                famh[(size_t)o * PSH + rowb + pxx + 1] = f2bf(acc[mi][ni][r] + cf);
            }
}

// ============ 3x3 conv 256->256: full-M 256o x 32px tiles + BN + ReLU =======
__global__ __launch_bounds__(256, 2) void conv2_k(
        const unsigned short* __restrict__ inh,   // 256 bf16 planes PSH, ring=0
        const unsigned short* __restrict__ wTh,   // [9][256][256] bf16
        const float* __restrict__ gam, const float* __restrict__ bet,
        const float* __restrict__ mean, const float* __restrict__ var,
        float* __restrict__ out_flat,             // [256][HW] f32
        unsigned short* __restrict__ out_padh) {  // optional bf16 planes
    __shared__ __align__(16) unsigned short Bs[32][40];
    __shared__ float scs[256], bis[256];
    int b = blockIdx.x;
    int xcd = b & 7, slot = b >> 3;
    int nt = (xcd << 6) + slot;
    int hrow = nt >> 2, pc0 = (nt & 3) << 5;
    int tid = threadIdx.x;
    int wv = tid >> 6, lane = tid & 63;
    int lr = lane & 15, lg = lane >> 4;
    int pxl = tid & 31, cg = tid >> 5;
    {
        float sc = gam[tid] * rsqrtf(var[tid] + 1e-5f);
        scs[tid] = sc;
        bis[tid] = bet[tid] - mean[tid] * sc;
    }
    f32x4 acc[4][2];
#pragma unroll
    for (int i = 0; i < 4; ++i)
#pragma unroll
        for (int j = 0; j < 2; ++j) acc[i][j] = (f32x4){0.f, 0.f, 0.f, 0.f};

    for (int kt = 0; kt < 9; ++kt) {
        int dy = kt / 3 - 1, dx = kt % 3 - 1;
        const unsigned short* src = inh + (size_t)(hrow + dy + 1) * SH + (pc0 + pxl + dx + 1);
        const unsigned short* wk  = wTh + (size_t)kt * 65536;
        for (int ks = 0; ks < 256; ks += 32) {
            __syncthreads();
            unsigned short pk[4];
#pragma unroll
            for (int e = 0; e < 4; ++e) {
                int c = ks + (cg << 2) + e;
                pk[e] = src[(size_t)c * PSH];
            }
            *(short4*)&Bs[pxl][cg << 2] = *(short4*)pk;
            __syncthreads();
            bf16x8 af[4], bfr[2];
#pragma unroll
            for (int mi = 0; mi < 4; ++mi) {
                int o = (wv << 6) + (mi << 4) + lr;
                af[mi] = *(const bf16x8*)(wk + (size_t)o * 256 + ks + (lg << 3));
            }
#pragma unroll
            for (int ni = 0; ni < 2; ++ni) {
                int n = (ni << 4) + lr;
                bfr[ni] = *(const bf16x8*)(&Bs[n][lg << 3]);
            }
#pragma unroll
            for (int mi = 0; mi < 4; ++mi)
#pragma unroll
                for (int ni = 0; ni < 2; ++ni)
                    acc[mi][ni] = __builtin_amdgcn_mfma_f32_16x16x32_bf16(
                        af[mi], bfr[ni], acc[mi][ni], 0, 0, 0);
        }
    }
    size_t rowb = (size_t)(hrow + 1) * SH;
#pragma unroll
    for (int mi = 0; mi < 4; ++mi)
#pragma unroll
        for (int ni = 0; ni < 2; ++ni)
#pragma unroll
            for (int r = 0; r < 4; ++r) {
                int o   = (wv << 6) + (mi << 4) + (lg << 2) + r;
                int pxx = pc0 + (ni << 4) + lr;
                float rv = fmaxf(acc[mi][ni][r] * scs[o] + bis[o], 0.0f);
                out_flat[(size_t)o * HW + (hrow << 7) + pxx] = rv;
                if (out_padh)
                    out_padh[(size_t)o * PSH + rowb + pxx + 1] = f2bf(rv);
            }
}

extern "C" void kernel_launch(void* const* d_in, const int* in_sizes, int n_in,
                              void* d_out, int out_size, void* d_ws, size_t ws_size,
                              hipStream_t stream) {
    const float* x     = (const float*)d_in[0];
    const float* llf   = (const float*)d_in[1];
    const float* fm_w  = (const float*)d_in[2];
    const float* fs_w  = (const float*)d_in[3];
    const float* p_w   = (const float*)d_in[4];
    const float* p_b   = (const float*)d_in[5];
    const float* dc_w  = (const float*)d_in[6];
    const float* lc1_w = (const float*)d_in[7];
    const float* bn1g  = (const float*)d_in[8];
    const float* bn1b  = (const float*)d_in[9];
    const float* bn1m  = (const float*)d_in[10];
    const float* bn1v  = (const float*)d_in[11];
    const float* lc2_w = (const float*)d_in[12];
    const float* bn2g  = (const float*)d_in[13];
    const float* bn2b  = (const float*)d_in[14];
    const float* bn2m  = (const float*)d_in[15];
    const float* bn2v  = (const float*)d_in[16];
    float* out1 = (float*)d_out;
    float* out2 = out1 + (size_t)256 * HW;

    if (ws_size < 68960256u) return;
    char* ws = (char*)d_ws;
    // R0 [0, 34,611,200): ccpad f32 (dead after cvt) -> pbuf @0 (8.39MB, dead
    //   after make_idx) -> famh @0 (8.79MB), up1h @9,000,000 (8.79MB)
    float*          ccpad = (float*)ws;
    float*          pbuf  = (float*)ws;
    unsigned short* famh  = (unsigned short*)ws;
    unsigned short* up1h  = (unsigned short*)(ws + 9000000);
    // R1 [34,611,200, +17,571,840): v f32 (dead after u_matmul) -> cch bf16
    float*          vbuf  = (float*)(ws + 34611200);
    unsigned short* cch   = (unsigned short*)(ws + 34611200);
    // R2 [52,183,040, +16,777,216): u f32 (dead after Cf) -> small tensors
    char* R2 = ws + 52183040;
    float*          ubuf   = (float*)R2;
    int4*           IDX    = (int4*)  (R2);                     // 2,359,296
    float4*         WT     = (float4*)(R2 + 2359296);           // 2,359,296
    unsigned short* dcwTh  = (unsigned short*)(R2 + 4718592);   // 2,359,296
    unsigned short* lcw1Th = (unsigned short*)(R2 + 7077888);   // 1,179,648
    unsigned short* lcw2Th = (unsigned short*)(R2 + 8257536);   // 1,179,648
    unsigned short* pwTh   = (unsigned short*)(R2 + 9437184);   //   294,912

    zero_ring_k<<<dim3(516), 256, 0, stream>>>(ccpad + (size_t)256 * PS, 256);
    upsample_k<<<dim3(67, 256), 256, 0, stream>>>(x, ccpad);
    gemm1x1_sig_k<<<dim3(16, 32), 256, 0, stream>>>(fm_w, llf, vbuf);
    u_matmul_k<<<dim3(2, 256), 256, 0, stream>>>(llf, vbuf, ubuf);
    gemm1x1_pad_k<<<dim3(16, 32), 256, 0, stream>>>(fs_w, ubuf, ccpad + (size_t)256 * PS);
    cvt_bf16_k<<<dim3(33800), 256, 0, stream>>>(ccpad, cch);   // v, u dead now
    tr_ocK_k<<<dim3(4608), 256, 0, stream>>>(dc_w, dcwTh, 512);
    tr_ocK_k<<<dim3(2304), 256, 0, stream>>>(lc1_w, lcw1Th, 256);
    tr_ocK_k<<<dim3(2304), 256, 0, stream>>>(lc2_w, lcw2Th, 256);
    tr_pw_k<<<dim3(576), 256, 0, stream>>>(p_w, pwTh);
    off_part_k<<<dim3(512), 256, 0, stream>>>(cch, pwTh, pbuf);     // ccpad dead
    make_idx_k<<<dim3(576), 256, 0, stream>>>(pbuf, p_b, IDX, WT);
    zero_ring_h_k<<<dim3(521), 256, 0, stream>>>(famh, 256);        // pbuf dead
    zero_ring_h_k<<<dim3(521), 256, 0, stream>>>(up1h, 256);
    fam2_k<<<dim3(512), 256, 0, stream>>>(cch, dcwTh, IDX, WT, famh);
    conv2_k<<<dim3(512), 256, 0, stream>>>(famh, lcw1Th, bn1g, bn1b, bn1m, bn1v,
                                           out1, up1h);
    conv2_k<<<dim3(512), 256, 0, stream>>>(up1h, lcw2Th, bn2g, bn2b, bn2m, bn2v,
                                           out2, nullptr);
}